// Round 2
// baseline (8438.799 us; speedup 1.0000x reference)
//
#include <hip/hip_runtime.h>

// Wave-level LDS ordering fence: waits all outstanding LDS ops, and the
// "memory" clobber stops the compiler reordering LDS accesses across it.
#define FENCE() asm volatile("s_waitcnt lgkmcnt(0)" ::: "memory")

__device__ __forceinline__ double dshfl_xor(double v, int m) {
  return __shfl_xor(v, m, 64);
}

// One block = 256 threads = 4 waves, one 32x32 SPD matrix per wave.
// Full fused pipeline in fp64 (correctness-first; see journal).
__global__ __launch_bounds__(256) void spd_fused(
    const float* __restrict__ xg,
    const float* __restrict__ w1g,
    const float* __restrict__ w2g,
    const float* __restrict__ w3g,
    const float* __restrict__ fcg,
    float* __restrict__ outg,
    int B)
{
  __shared__ double slot[4][2240];   // per-wave workspace (17.5 KB each)
  __shared__ float  wsh[1632];       // w1(1024) w2(512) w3(64) fc(32), fp32

  const int tid  = threadIdx.x;
  const int wid  = tid >> 6;
  const int lane = tid & 63;

  for (int i = tid; i < 1024; i += 256) wsh[i] = w1g[i];
  for (int i = tid; i < 512;  i += 256) wsh[1024 + i] = w2g[i];
  if (tid < 64) wsh[1536 + tid] = w3g[tid];
  if (tid < 32) wsh[1600 + tid] = fcg[tid];
  __syncthreads();   // only block-wide barrier; waves independent after this

  const float* w1s = wsh;
  const float* w2s = wsh + 1024;
  const float* w3s = wsh + 1536;
  const float* fcs = wsh + 1600;

  double* G    = slot[wid];          // stage1: col-major stride 33 (32 cols); stage2: stride 17
  double* T    = slot[wid] + 1056;   // 1024: x / T / P buffers
  double* invA = slot[wid] + 2080;   // 32
  double* dclA = slot[wid] + 2112;   // 32
  double* Qb   = slot[wid] + 2144;   // 64
  double* fb   = slot[wid] + 2208;   // 16

  const long b = (long)blockIdx.x * 4 + wid;
  if (b >= B) return;

  // ---------------- load x (fp32) -> G as row-major [32][32] (stride 32), fp64
  {
    const float4* xv = (const float4*)(xg + (size_t)b * 1024);
    #pragma unroll
    for (int jj = 0; jj < 4; ++jj) {
      int i4 = lane + 64 * jj;
      float4 v = xv[i4];
      double* d = G + (size_t)i4 * 4;
      d[0] = (double)v.x; d[1] = (double)v.y; d[2] = (double)v.z; d[3] = (double)v.w;
    }
  }
  FENCE();

  // ---------------- T = x * w1   (T[r][j], stride 32)
  {
    const int h = lane >> 5;      // 0/1
    const int j = lane & 31;
    double acc[16];
    #pragma unroll
    for (int e = 0; e < 16; ++e) acc[e] = 0.0;
    #pragma unroll 1
    for (int c = 0; c < 32; ++c) {
      double wv = (double)w1s[c * 32 + j];
      #pragma unroll
      for (int e = 0; e < 16; ++e)
        acc[e] += G[(2 * e + h) * 32 + c] * wv;
    }
    #pragma unroll
    for (int e = 0; e < 16; ++e) T[(2 * e + h) * 32 + j] = acc[e];
  }
  FENCE();

  // ---------------- M1 = w1^T * T  -> G col-major (stride 33). x in G is dead.
  {
    const int h = lane >> 5;
    const int j = lane & 31;
    double acc[16];
    #pragma unroll
    for (int e = 0; e < 16; ++e) acc[e] = 0.0;
    #pragma unroll 1
    for (int r = 0; r < 32; ++r) {
      double tv = T[r * 32 + j];
      #pragma unroll
      for (int e = 0; e < 16; ++e)
        acc[e] += (double)w1s[r * 32 + (2 * e + h)] * tv;
    }
    #pragma unroll
    for (int e = 0; e < 16; ++e) G[j * 33 + (2 * e + h)] = acc[e];  // col j, row i
  }
  FENCE();

  // ---------------- one-sided Jacobi, n=32 (16 pairs/round, 4 lanes/pair)
  {
    const int g4 = lane >> 2;
    const int rb = (lane & 3) * 8;
    #pragma unroll 1
    for (int sweep = 0; sweep < 12; ++sweep) {
      double offmax = 0.0;
      #pragma unroll 1
      for (int r = 0; r < 31; ++r) {
        int p, q;
        if (g4 == 0) { p = 31; q = r % 31; }
        else { p = (r + g4) % 31; q = (r + 31 - g4) % 31; }
        double gp[8], gq[8];
        double sa = 0.0, sb = 0.0, sg = 0.0;
        #pragma unroll
        for (int i = 0; i < 8; ++i) {
          double a = G[p * 33 + rb + i];
          double c = G[q * 33 + rb + i];
          gp[i] = a; gq[i] = c;
          sa += a * a; sb += c * c; sg += a * c;
        }
        sa += dshfl_xor(sa, 1); sb += dshfl_xor(sb, 1); sg += dshfl_xor(sg, 1);
        sa += dshfl_xor(sa, 2); sb += dshfl_xor(sb, 2); sg += dshfl_xor(sg, 2);
        double dn  = sa * sb;
        double rel = (dn > 0.0) ? (sg * sg) / dn : 0.0;
        offmax = fmax(offmax, rel);
        if (rel > 1e-30) {
          double u = 0.5 * (sb - sa);
          double R = sqrt(u * u + sg * sg);
          double t = sg / (u + ((u >= 0.0) ? R : -R));
          double c2 = rsqrt(1.0 + t * t);
          double s2 = c2 * t;
          #pragma unroll
          for (int i = 0; i < 8; ++i) {
            double a = gp[i], c = gq[i];
            G[p * 33 + rb + i] = c2 * a - s2 * c;
            G[q * 33 + rb + i] = s2 * a + c2 * c;
          }
        }
        FENCE();
      }
      #pragma unroll
      for (int m = 1; m <= 32; m <<= 1) offmax = fmax(offmax, dshfl_xor(offmax, m));
      if (offmax < 1e-26) break;
    }
  }

  // ---------------- lambda_1, ReEig clamp
  if (lane < 32) {
    int k = lane;
    double ss = 0.0;
    #pragma unroll 1
    for (int r2 = 0; r2 < 32; ++r2) { double v = G[k * 33 + r2]; ss += v * v; }
    double lam = sqrt(ss);
    invA[k] = (lam > 1e-150) ? (1.0 / lam) : 0.0;
    dclA[k] = fmax(lam, 1e-4);
  }
  FENCE();

  // ---------------- P = V1^T w2  -> T (stride 17), 32x16
  {
    const int k  = lane & 31;
    const int jb = (lane >> 5) * 8;
    double acc[8];
    #pragma unroll
    for (int e = 0; e < 8; ++e) acc[e] = 0.0;
    #pragma unroll 1
    for (int r = 0; r < 32; ++r) {
      double gv = G[k * 33 + r];
      #pragma unroll
      for (int e = 0; e < 8; ++e)
        acc[e] += gv * (double)w2s[r * 16 + jb + e];
    }
    double iv = invA[k];
    #pragma unroll
    for (int e = 0; e < 8; ++e) T[k * 17 + jb + e] = acc[e] * iv;
  }
  FENCE();

  // ---------------- M2 = P^T diag(d1) P -> G col-major (stride 17), 16x16
  {
    #pragma unroll
    for (int e = 0; e < 4; ++e) {
      int idx = lane + 64 * e;
      int i2 = idx >> 4, j2 = idx & 15;
      double acc = 0.0;
      #pragma unroll 1
      for (int k = 0; k < 32; ++k)
        acc += dclA[k] * T[k * 17 + i2] * T[k * 17 + j2];
      G[j2 * 17 + i2] = acc;
    }
  }
  FENCE();

  // ---------------- one-sided Jacobi, n=16 (8 pairs/round, 8 lanes/pair)
  {
    const int g8 = lane >> 3;
    const int rb = (lane & 7) * 2;
    #pragma unroll 1
    for (int sweep = 0; sweep < 10; ++sweep) {
      double offmax = 0.0;
      #pragma unroll 1
      for (int r = 0; r < 15; ++r) {
        int p, q;
        if (g8 == 0) { p = 15; q = r % 15; }
        else { p = (r + g8) % 15; q = (r + 15 - g8) % 15; }
        double a0 = G[p * 17 + rb], a1 = G[p * 17 + rb + 1];
        double c0 = G[q * 17 + rb], c1 = G[q * 17 + rb + 1];
        double sa = a0 * a0 + a1 * a1;
        double sb = c0 * c0 + c1 * c1;
        double sg = a0 * c0 + a1 * c1;
        sa += dshfl_xor(sa, 1); sb += dshfl_xor(sb, 1); sg += dshfl_xor(sg, 1);
        sa += dshfl_xor(sa, 2); sb += dshfl_xor(sb, 2); sg += dshfl_xor(sg, 2);
        sa += dshfl_xor(sa, 4); sb += dshfl_xor(sb, 4); sg += dshfl_xor(sg, 4);
        double dn  = sa * sb;
        double rel = (dn > 0.0) ? (sg * sg) / dn : 0.0;
        offmax = fmax(offmax, rel);
        if (rel > 1e-30) {
          double u = 0.5 * (sb - sa);
          double R = sqrt(u * u + sg * sg);
          double t = sg / (u + ((u >= 0.0) ? R : -R));
          double cc = rsqrt(1.0 + t * t);
          double ss = cc * t;
          G[p * 17 + rb]     = cc * a0 - ss * c0;
          G[p * 17 + rb + 1] = cc * a1 - ss * c1;
          G[q * 17 + rb]     = ss * a0 + cc * c0;
          G[q * 17 + rb + 1] = ss * a1 + cc * c1;
        }
        FENCE();
      }
      #pragma unroll
      for (int m = 1; m <= 32; m <<= 1) offmax = fmax(offmax, dshfl_xor(offmax, m));
      if (offmax < 1e-26) break;
    }
  }

  // ---------------- lambda_2, ReEig clamp
  if (lane < 16) {
    int k = lane;
    double ss = 0.0;
    #pragma unroll 1
    for (int r2 = 0; r2 < 16; ++r2) { double v = G[k * 17 + r2]; ss += v * v; }
    double lam = sqrt(ss);
    invA[k] = (lam > 1e-150) ? (1.0 / lam) : 0.0;
    dclA[k] = fmax(lam, 1e-4);
  }
  FENCE();

  // ---------------- Qb[k][j] = (V2^T w3)[k][j] * sqrt(d2_k)   (16x4)
  {
    const int k = lane >> 2;
    const int j = lane & 3;
    double acc = 0.0;
    #pragma unroll 1
    for (int r = 0; r < 16; ++r)
      acc += G[k * 17 + r] * (double)w3s[r * 4 + j];
    Qb[k * 4 + j] = acc * invA[k] * sqrt(dclA[k]);
  }
  FENCE();

  // ---------------- stage 3: per-lane redundant 4x4 LogEig (M3 = Qb^T Qb)
  double g3[4][4];  // g3[c][r]: column c of working matrix
  {
    double M[4][4];
    #pragma unroll
    for (int i = 0; i < 4; ++i)
      #pragma unroll
      for (int j = 0; j < 4; ++j) M[i][j] = 0.0;
    #pragma unroll 1
    for (int k = 0; k < 16; ++k) {
      double q0 = Qb[4 * k], q1 = Qb[4 * k + 1], q2 = Qb[4 * k + 2], q3 = Qb[4 * k + 3];
      M[0][0] += q0 * q0; M[0][1] += q0 * q1; M[0][2] += q0 * q2; M[0][3] += q0 * q3;
      M[1][1] += q1 * q1; M[1][2] += q1 * q2; M[1][3] += q1 * q3;
      M[2][2] += q2 * q2; M[2][3] += q2 * q3; M[3][3] += q3 * q3;
    }
    M[1][0] = M[0][1]; M[2][0] = M[0][2]; M[3][0] = M[0][3];
    M[2][1] = M[1][2]; M[3][1] = M[1][3]; M[3][2] = M[2][3];
    #pragma unroll
    for (int c = 0; c < 4; ++c)
      #pragma unroll
      for (int r = 0; r < 4; ++r) g3[c][r] = M[r][c];
  }

  {
    #define ROT4(P,Q) do { \
      double sa = g3[P][0]*g3[P][0]+g3[P][1]*g3[P][1]+g3[P][2]*g3[P][2]+g3[P][3]*g3[P][3]; \
      double sb = g3[Q][0]*g3[Q][0]+g3[Q][1]*g3[Q][1]+g3[Q][2]*g3[Q][2]+g3[Q][3]*g3[Q][3]; \
      double sg = g3[P][0]*g3[Q][0]+g3[P][1]*g3[Q][1]+g3[P][2]*g3[Q][2]+g3[P][3]*g3[Q][3]; \
      double dn = sa*sb; double rel = (dn > 0.0) ? (sg*sg)/dn : 0.0; \
      off3 = fmax(off3, rel); \
      if (rel > 1e-30) { \
        double u_ = 0.5*(sb - sa); \
        double R_ = sqrt(u_*u_ + sg*sg); \
        double t_ = sg / (u_ + ((u_ >= 0.0) ? R_ : -R_)); \
        double c_ = rsqrt(1.0 + t_*t_); double s_ = c_*t_; \
        double a0_=g3[P][0], b0_=g3[Q][0]; g3[P][0]=c_*a0_-s_*b0_; g3[Q][0]=s_*a0_+c_*b0_; \
        double a1_=g3[P][1], b1_=g3[Q][1]; g3[P][1]=c_*a1_-s_*b1_; g3[Q][1]=s_*a1_+c_*b1_; \
        double a2_=g3[P][2], b2_=g3[Q][2]; g3[P][2]=c_*a2_-s_*b2_; g3[Q][2]=s_*a2_+c_*b2_; \
        double a3_=g3[P][3], b3_=g3[Q][3]; g3[P][3]=c_*a3_-s_*b3_; g3[Q][3]=s_*a3_+c_*b3_; \
      } } while (0)

    #pragma unroll 1
    for (int sweep = 0; sweep < 8; ++sweep) {
      double off3 = 0.0;
      ROT4(0,1); ROT4(0,2); ROT4(0,3); ROT4(1,2); ROT4(1,3); ROT4(2,3);
      if (off3 < 1e-26) break;
    }
    #undef ROT4
  }

  // eigen extraction + LogEig reconstruction
  double lw[4];
  #pragma unroll
  for (int c = 0; c < 4; ++c) {
    double ss = g3[c][0]*g3[c][0] + g3[c][1]*g3[c][1] + g3[c][2]*g3[c][2] + g3[c][3]*g3[c][3];
    double lam = sqrt(ss);
    lw[c] = log(fmax(lam, 1e-10));
    double iv = (lam > 1e-150) ? (1.0 / lam) : 0.0;
    #pragma unroll
    for (int r = 0; r < 4; ++r) g3[c][r] *= iv;
  }

  double X3[4][4];
  #pragma unroll
  for (int i = 0; i < 4; ++i)
    #pragma unroll
    for (int j = 0; j < 4; ++j)
      X3[i][j] = lw[0]*g3[0][i]*g3[0][j] + lw[1]*g3[1][i]*g3[1][j]
               + lw[2]*g3[2][i]*g3[2][j] + lw[3]*g3[3][i]*g3[3][j];

  // FC + log_softmax (redundant per lane)
  double l0 = 0.0, l1 = 0.0;
  #pragma unroll
  for (int m = 0; m < 16; ++m) {
    double f = X3[m >> 2][m & 3];
    l0 += f * (double)fcs[2 * m];
    l1 += f * (double)fcs[2 * m + 1];
  }
  double mx  = fmax(l0, l1);
  double lse = mx + log(exp(l0 - mx) + exp(l1 - mx));

  // bounce feat through LDS to avoid dynamic register indexing on write
  if (lane == 0) {
    #pragma unroll
    for (int m = 0; m < 16; ++m) fb[m] = X3[m >> 2][m & 3];
  }
  FENCE();

  float* outFeat = outg + (size_t)B * 2;
  if (lane < 16) outFeat[(size_t)b * 16 + lane] = (float)fb[lane];
  if (lane < 2)  outg[(size_t)b * 2 + lane] = (float)((lane == 0 ? l0 : l1) - lse);
}

extern "C" void kernel_launch(void* const* d_in, const int* in_sizes, int n_in,
                              void* d_out, int out_size, void* d_ws, size_t ws_size,
                              hipStream_t stream) {
  const float* x  = (const float*)d_in[0];
  const float* w1 = (const float*)d_in[1];
  const float* w2 = (const float*)d_in[2];
  const float* w3 = (const float*)d_in[3];
  const float* fc = (const float*)d_in[4];
  float* out = (float*)d_out;
  int B = in_sizes[0] / 1024;
  int grid = (B + 3) / 4;
  hipLaunchKernelGGL(spd_fused, dim3(grid), dim3(256), 0, stream,
                     x, w1, w2, w3, fc, out, B);
}

// Round 3
// 3317.448 us; speedup vs baseline: 2.5438x; 2.5438x over previous
//
#include <hip/hip_runtime.h>

// Wave-level LDS ordering fence: waits all outstanding LDS ops; "memory"
// clobber stops compiler reordering LDS accesses across it. Waves are
// independent after the initial __syncthreads, so no barriers needed.
#define FENCE() asm volatile("s_waitcnt lgkmcnt(0)" ::: "memory")

__device__ __forceinline__ float fshfl_xor(float v, int m) {
  return __shfl_xor(v, m, 64);
}

// One block = 256 threads = 4 waves, one 32x32 SPD matrix per wave.
// fp32 Jacobi (hot loops) + fp64 one-shot accumulations + fp64 4x4 stage-3.
// LDS: 4*2144*4 + 1632*4 = 40832 B -> 4 blocks/CU (16 waves/CU).
__global__ __launch_bounds__(256, 4) void spd_fused(
    const float* __restrict__ xg,
    const float* __restrict__ w1g,
    const float* __restrict__ w2g,
    const float* __restrict__ w3g,
    const float* __restrict__ fcg,
    float* __restrict__ outg,
    int B)
{
  __shared__ float slot[4][2144];
  __shared__ float wsh[1632];     // w1(1024) w2(512) w3(64) fc(32)

  const int tid  = threadIdx.x;
  const int wid  = tid >> 6;
  const int lane = tid & 63;

  for (int i = tid; i < 1024; i += 256) wsh[i] = w1g[i];
  for (int i = tid; i < 512;  i += 256) wsh[1024 + i] = w2g[i];
  if (tid < 64) wsh[1536 + tid] = w3g[tid];
  if (tid < 32) wsh[1600 + tid] = fcg[tid];
  __syncthreads();   // only block-wide barrier

  const float* w1s = wsh;
  const float* w2s = wsh + 1024;
  const float* w3s = wsh + 1536;
  const float* fcs = wsh + 1600;

  float* A    = slot[wid];          // 1056: Tmat(1024) -> P(542) -> Qb(64) + fb(@128)
  float* Cc   = slot[wid] + 1056;   // 1024: x -> swizzled V1 cols -> M2/V2 (stride 17)
  float* invA = slot[wid] + 2080;   // 32
  float* dclA = slot[wid] + 2112;   // 32

  const long b = (long)blockIdx.x * 4 + wid;
  if (b >= B) return;

  // ---------------- load x (fp32) -> Cc row-major [32][32]
  {
    const float4* xv = (const float4*)(xg + (size_t)b * 1024);
    #pragma unroll
    for (int jj = 0; jj < 4; ++jj) {
      int i4 = lane + 64 * jj;
      *(float4*)(Cc + i4 * 4) = xv[i4];
    }
  }
  FENCE();

  // ---------------- Tmat = x * w1 -> A row-major (fp64 acc)
  {
    const int h = lane >> 5;      // 0/1
    const int j = lane & 31;
    double acc[16];
    #pragma unroll
    for (int e = 0; e < 16; ++e) acc[e] = 0.0;
    #pragma unroll 1
    for (int c = 0; c < 32; ++c) {
      double wv = (double)w1s[c * 32 + j];
      #pragma unroll
      for (int e = 0; e < 16; ++e)
        acc[e] += (double)Cc[(2 * e + h) * 32 + c] * wv;
    }
    #pragma unroll
    for (int e = 0; e < 16; ++e) A[(2 * e + h) * 32 + j] = (float)acc[e];
  }
  FENCE();

  // ---------------- M1 = w1^T * Tmat -> Cc, swizzled-quad column-major.
  // Column p, quad qd (rows 4qd..4qd+3) lives at p*32 + ((qd+p)&7)*4.
  {
    const int h = lane >> 5;
    const int j = lane & 31;   // owns column j
    double acc[16];
    #pragma unroll
    for (int e = 0; e < 16; ++e) acc[e] = 0.0;
    #pragma unroll 1
    for (int r = 0; r < 32; ++r) {
      double tv = (double)A[r * 32 + j];
      #pragma unroll
      for (int e = 0; e < 16; ++e)
        acc[e] += (double)w1s[r * 32 + (2 * e + h)] * tv;
    }
    #pragma unroll
    for (int e = 0; e < 16; ++e) {
      int i = 2 * e + h;
      Cc[j * 32 + (((i >> 2) + j & 7) << 2) + (i & 3)] = (float)acc[e];
    }
  }
  FENCE();

  // ---------------- one-sided Jacobi, n=32 (16 pairs/round, 4 lanes/pair)
  {
    const int g4 = lane >> 2;
    const int c2 = (lane & 3) << 1;   // this lane handles quads c2, c2+1
    #pragma unroll 1
    for (int sweep = 0; sweep < 10; ++sweep) {
      float offmax = 0.f;
      #pragma unroll 1
      for (int r = 0; r < 31; ++r) {
        int p, q;
        if (g4 == 0) { p = 31; q = r; }
        else { p = (r + g4) % 31; q = (r + 31 - g4) % 31; }
        const int pa0 = p * 32 + (((c2 + p) & 7) << 2);
        const int pa1 = p * 32 + (((c2 + 1 + p) & 7) << 2);
        const int qa0 = q * 32 + (((c2 + q) & 7) << 2);
        const int qa1 = q * 32 + (((c2 + 1 + q) & 7) << 2);
        float4 a0 = *(const float4*)(Cc + pa0);
        float4 a1 = *(const float4*)(Cc + pa1);
        float4 b0 = *(const float4*)(Cc + qa0);
        float4 b1 = *(const float4*)(Cc + qa1);
        float sa = a0.x*a0.x + a0.y*a0.y + a0.z*a0.z + a0.w*a0.w
                 + a1.x*a1.x + a1.y*a1.y + a1.z*a1.z + a1.w*a1.w;
        float sb = b0.x*b0.x + b0.y*b0.y + b0.z*b0.z + b0.w*b0.w
                 + b1.x*b1.x + b1.y*b1.y + b1.z*b1.z + b1.w*b1.w;
        float sg = a0.x*b0.x + a0.y*b0.y + a0.z*b0.z + a0.w*b0.w
                 + a1.x*b1.x + a1.y*b1.y + a1.z*b1.z + a1.w*b1.w;
        sa += fshfl_xor(sa, 1); sb += fshfl_xor(sb, 1); sg += fshfl_xor(sg, 1);
        sa += fshfl_xor(sa, 2); sb += fshfl_xor(sb, 2); sg += fshfl_xor(sg, 2);
        float dn  = sa * sb;
        float rel = (dn > 0.f) ? (sg * sg) / dn : 0.f;
        offmax = fmaxf(offmax, rel);
        if (rel > 1e-13f) {          // skip sub-fp32-resolution rotations
          float u  = 0.5f * (sb - sa);
          float R  = sqrtf(u * u + sg * sg);
          float t  = sg / (u + ((u >= 0.f) ? R : -R));
          float ct = rsqrtf(1.f + t * t);
          float st = ct * t;
          float4 n0, n1, m0, m1;
          n0.x = ct*a0.x - st*b0.x;  m0.x = st*a0.x + ct*b0.x;
          n0.y = ct*a0.y - st*b0.y;  m0.y = st*a0.y + ct*b0.y;
          n0.z = ct*a0.z - st*b0.z;  m0.z = st*a0.z + ct*b0.z;
          n0.w = ct*a0.w - st*b0.w;  m0.w = st*a0.w + ct*b0.w;
          n1.x = ct*a1.x - st*b1.x;  m1.x = st*a1.x + ct*b1.x;
          n1.y = ct*a1.y - st*b1.y;  m1.y = st*a1.y + ct*b1.y;
          n1.z = ct*a1.z - st*b1.z;  m1.z = st*a1.z + ct*b1.z;
          n1.w = ct*a1.w - st*b1.w;  m1.w = st*a1.w + ct*b1.w;
          *(float4*)(Cc + pa0) = n0; *(float4*)(Cc + pa1) = n1;
          *(float4*)(Cc + qa0) = m0; *(float4*)(Cc + qa1) = m1;
        }
        FENCE();
      }
      #pragma unroll
      for (int m = 1; m <= 32; m <<= 1) offmax = fmaxf(offmax, fshfl_xor(offmax, m));
      if (offmax < 1e-12f) break;
    }
  }

  // ---------------- lambda_1 (fp64 norm), ReEig clamp
  if (lane < 32) {
    const int k = lane;
    double ss = 0.0;
    #pragma unroll
    for (int qd = 0; qd < 8; ++qd) {
      float4 v = *(const float4*)(Cc + k * 32 + (((qd + k) & 7) << 2));
      ss += (double)v.x * v.x + (double)v.y * v.y + (double)v.z * v.z + (double)v.w * v.w;
    }
    double lam = sqrt(ss);
    invA[k] = (lam > 0.0) ? (float)(1.0 / lam) : 0.f;
    dclA[k] = (float)fmax(lam, 1e-4);
  }
  FENCE();

  // ---------------- P = V1^T w2 -> A (stride 17), fp64 acc
  {
    const int k  = lane & 31;
    const int jb = (lane >> 5) << 3;
    double acc[8];
    #pragma unroll
    for (int e = 0; e < 8; ++e) acc[e] = 0.0;
    #pragma unroll 1
    for (int qd = 0; qd < 8; ++qd) {
      float4 v = *(const float4*)(Cc + k * 32 + (((qd + k) & 7) << 2));
      const int r0 = qd << 2;
      #pragma unroll
      for (int e = 0; e < 8; ++e) {
        acc[e] += (double)v.x * (double)w2s[ r0      * 16 + jb + e]
                + (double)v.y * (double)w2s[(r0 + 1) * 16 + jb + e]
                + (double)v.z * (double)w2s[(r0 + 2) * 16 + jb + e]
                + (double)v.w * (double)w2s[(r0 + 3) * 16 + jb + e];
      }
    }
    double iv = (double)invA[k];
    #pragma unroll
    for (int e = 0; e < 8; ++e) A[k * 17 + jb + e] = (float)(acc[e] * iv);
  }
  FENCE();

  // ---------------- M2 = P^T diag(d1) P -> Cc col-major (stride 17), fp64 acc
  {
    #pragma unroll
    for (int e = 0; e < 4; ++e) {
      int idx = lane + (e << 6);
      int i2 = idx >> 4, j2 = idx & 15;
      double acc = 0.0;
      #pragma unroll 1
      for (int k = 0; k < 32; ++k)
        acc += (double)dclA[k] * ((double)A[k * 17 + i2] * (double)A[k * 17 + j2]);
      Cc[j2 * 17 + i2] = (float)acc;
    }
  }
  FENCE();

  // ---------------- one-sided Jacobi, n=16 (8 pairs/round, 8 lanes/pair)
  {
    const int g8 = lane >> 3;
    const int rb = (lane & 7) * 2;
    #pragma unroll 1
    for (int sweep = 0; sweep < 8; ++sweep) {
      float offmax = 0.f;
      #pragma unroll 1
      for (int r = 0; r < 15; ++r) {
        int p, q;
        if (g8 == 0) { p = 15; q = r; }
        else { p = (r + g8) % 15; q = (r + 15 - g8) % 15; }
        float a0 = Cc[p * 17 + rb], a1 = Cc[p * 17 + rb + 1];
        float c0 = Cc[q * 17 + rb], c1 = Cc[q * 17 + rb + 1];
        float sa = a0 * a0 + a1 * a1;
        float sb = c0 * c0 + c1 * c1;
        float sg = a0 * c0 + a1 * c1;
        sa += fshfl_xor(sa, 1); sb += fshfl_xor(sb, 1); sg += fshfl_xor(sg, 1);
        sa += fshfl_xor(sa, 2); sb += fshfl_xor(sb, 2); sg += fshfl_xor(sg, 2);
        sa += fshfl_xor(sa, 4); sb += fshfl_xor(sb, 4); sg += fshfl_xor(sg, 4);
        float dn  = sa * sb;
        float rel = (dn > 0.f) ? (sg * sg) / dn : 0.f;
        offmax = fmaxf(offmax, rel);
        if (rel > 1e-13f) {
          float u  = 0.5f * (sb - sa);
          float R  = sqrtf(u * u + sg * sg);
          float t  = sg / (u + ((u >= 0.f) ? R : -R));
          float ct = rsqrtf(1.f + t * t);
          float st = ct * t;
          Cc[p * 17 + rb]     = ct * a0 - st * c0;
          Cc[p * 17 + rb + 1] = ct * a1 - st * c1;
          Cc[q * 17 + rb]     = st * a0 + ct * c0;
          Cc[q * 17 + rb + 1] = st * a1 + ct * c1;
        }
        FENCE();
      }
      #pragma unroll
      for (int m = 1; m <= 32; m <<= 1) offmax = fmaxf(offmax, fshfl_xor(offmax, m));
      if (offmax < 1e-12f) break;
    }
  }

  // ---------------- lambda_2 (fp64 norm), ReEig clamp
  if (lane < 16) {
    const int k = lane;
    double ss = 0.0;
    #pragma unroll
    for (int r2 = 0; r2 < 16; ++r2) { double v = (double)Cc[k * 17 + r2]; ss += v * v; }
    double lam = sqrt(ss);
    invA[k] = (lam > 0.0) ? (float)(1.0 / lam) : 0.f;
    dclA[k] = (float)fmax(lam, 1e-4);
  }
  FENCE();

  // ---------------- Qb[k][j] = (V2^T w3)[k][j] * sqrt(d2_k) -> A[0..63], fp64 acc
  {
    const int k = lane >> 2;
    const int j = lane & 3;
    double acc = 0.0;
    #pragma unroll 1
    for (int r = 0; r < 16; ++r)
      acc += (double)Cc[k * 17 + r] * (double)w3s[r * 4 + j];
    double scale = (double)invA[k] * sqrt((double)dclA[k]);
    A[k * 4 + j] = (float)(acc * scale);
  }
  FENCE();

  // ---------------- stage 3: per-lane redundant 4x4 LogEig in fp64
  double g3[4][4];  // g3[c][r]: column c of working matrix
  {
    double M[4][4];
    #pragma unroll
    for (int i = 0; i < 4; ++i)
      #pragma unroll
      for (int j = 0; j < 4; ++j) M[i][j] = 0.0;
    #pragma unroll 1
    for (int k = 0; k < 16; ++k) {
      float4 qv = *(const float4*)(A + (k << 2));   // broadcast read
      double q0 = qv.x, q1 = qv.y, q2 = qv.z, q3 = qv.w;
      M[0][0] += q0 * q0; M[0][1] += q0 * q1; M[0][2] += q0 * q2; M[0][3] += q0 * q3;
      M[1][1] += q1 * q1; M[1][2] += q1 * q2; M[1][3] += q1 * q3;
      M[2][2] += q2 * q2; M[2][3] += q2 * q3; M[3][3] += q3 * q3;
    }
    M[1][0] = M[0][1]; M[2][0] = M[0][2]; M[3][0] = M[0][3];
    M[2][1] = M[1][2]; M[3][1] = M[1][3]; M[3][2] = M[2][3];
    #pragma unroll
    for (int c = 0; c < 4; ++c)
      #pragma unroll
      for (int r = 0; r < 4; ++r) g3[c][r] = M[r][c];
  }

  {
    #define ROT4(P,Q) do { \
      double sa = g3[P][0]*g3[P][0]+g3[P][1]*g3[P][1]+g3[P][2]*g3[P][2]+g3[P][3]*g3[P][3]; \
      double sb = g3[Q][0]*g3[Q][0]+g3[Q][1]*g3[Q][1]+g3[Q][2]*g3[Q][2]+g3[Q][3]*g3[Q][3]; \
      double sg = g3[P][0]*g3[Q][0]+g3[P][1]*g3[Q][1]+g3[P][2]*g3[Q][2]+g3[P][3]*g3[Q][3]; \
      double dn = sa*sb; double rel = (dn > 0.0) ? (sg*sg)/dn : 0.0; \
      off3 = fmax(off3, rel); \
      if (rel > 1e-30) { \
        double u_ = 0.5*(sb - sa); \
        double R_ = sqrt(u_*u_ + sg*sg); \
        double t_ = sg / (u_ + ((u_ >= 0.0) ? R_ : -R_)); \
        double c_ = rsqrt(1.0 + t_*t_); double s_ = c_*t_; \
        double a0_=g3[P][0], b0_=g3[Q][0]; g3[P][0]=c_*a0_-s_*b0_; g3[Q][0]=s_*a0_+c_*b0_; \
        double a1_=g3[P][1], b1_=g3[Q][1]; g3[P][1]=c_*a1_-s_*b1_; g3[Q][1]=s_*a1_+c_*b1_; \
        double a2_=g3[P][2], b2_=g3[Q][2]; g3[P][2]=c_*a2_-s_*b2_; g3[Q][2]=s_*a2_+c_*b2_; \
        double a3_=g3[P][3], b3_=g3[Q][3]; g3[P][3]=c_*a3_-s_*b3_; g3[Q][3]=s_*a3_+c_*b3_; \
      } } while (0)

    #pragma unroll 1
    for (int sweep = 0; sweep < 8; ++sweep) {
      double off3 = 0.0;
      ROT4(0,1); ROT4(0,2); ROT4(0,3); ROT4(1,2); ROT4(1,3); ROT4(2,3);
      if (off3 < 1e-26) break;
    }
    #undef ROT4
  }

  // eigen extraction + LogEig values
  double lw[4];
  #pragma unroll
  for (int c = 0; c < 4; ++c) {
    double ss = g3[c][0]*g3[c][0] + g3[c][1]*g3[c][1] + g3[c][2]*g3[c][2] + g3[c][3]*g3[c][3];
    double lam = sqrt(ss);
    lw[c] = log(fmax(lam, 1e-10));
    double iv = (lam > 1e-150) ? (1.0 / lam) : 0.0;
    #pragma unroll
    for (int r = 0; r < 4; ++r) g3[c][r] *= iv;
  }

  // feat + FC + log_softmax, computing X3 entries on the fly
  double l0 = 0.0, l1 = 0.0;
  #pragma unroll
  for (int m = 0; m < 16; ++m) {
    const int i = m >> 2, j = m & 3;
    double f = lw[0]*g3[0][i]*g3[0][j] + lw[1]*g3[1][i]*g3[1][j]
             + lw[2]*g3[2][i]*g3[2][j] + lw[3]*g3[3][i]*g3[3][j];
    if (lane == 0) A[128 + m] = (float)f;   // fb staging
    l0 += f * (double)fcs[2 * m];
    l1 += f * (double)fcs[2 * m + 1];
  }
  double mx  = fmax(l0, l1);
  double lse = mx + log(exp(l0 - mx) + exp(l1 - mx));
  FENCE();

  float* outFeat = outg + (size_t)B * 2;
  if (lane < 16) outFeat[(size_t)b * 16 + lane] = A[128 + lane];
  if (lane < 2)  outg[(size_t)b * 2 + lane] = (float)((lane == 0 ? l0 : l1) - lse);
}

extern "C" void kernel_launch(void* const* d_in, const int* in_sizes, int n_in,
                              void* d_out, int out_size, void* d_ws, size_t ws_size,
                              hipStream_t stream) {
  const float* x  = (const float*)d_in[0];
  const float* w1 = (const float*)d_in[1];
  const float* w2 = (const float*)d_in[2];
  const float* w3 = (const float*)d_in[3];
  const float* fc = (const float*)d_in[4];
  float* out = (float*)d_out;
  int B = in_sizes[0] / 1024;
  int grid = (B + 3) / 4;
  hipLaunchKernelGGL(spd_fused, dim3(grid), dim3(256), 0, stream,
                     x, w1, w2, w3, fc, out, B);
}